// Round 20
// baseline (104.421 us; speedup 1.0000x reference)
//
#include <hip/hip_runtime.h>
#include <hip/hip_bf16.h>
#include <math.h>

#define EPS 1e-6f
#define LOG2E 1.44269504088896340736f

typedef __attribute__((ext_vector_type(8))) short short8;
typedef __attribute__((ext_vector_type(4))) short short4v;
typedef __attribute__((ext_vector_type(4))) float f32x4;
typedef __attribute__((ext_vector_type(16))) float f32x16;

// f32 -> bf16 (round-to-nearest-even)
static __device__ __forceinline__ short f2bf(float x) {
    unsigned u = __builtin_bit_cast(unsigned, x);
    u += 0x7fffu + ((u >> 16) & 1u);
    return (short)(u >> 16);
}
// bf16 -> f32
static __device__ __forceinline__ float bf2f(short s) {
    unsigned u = ((unsigned)(unsigned short)s) << 16;
    return __builtin_bit_cast(float, u);
}

typedef __attribute__((address_space(1))) const void gvoid_t;
typedef __attribute__((address_space(3))) void lvoid_t;
static __device__ __forceinline__ void gload_lds16(const void* g, void* l) {
    __builtin_amdgcn_global_load_lds((gvoid_t*)g, (lvoid_t*)l, 16, 0, 0);
}

// ---------------------------------------------------------------------------
// Combined input prep: x cast (blocks [0,2048)) + all 4 weight transposes
// (blocks [2048, 2688)) in one dispatch.
// ---------------------------------------------------------------------------
__global__ __launch_bounds__(256) void prep_inputs(
    const float* __restrict__ x, const float* __restrict__ Wq,
    const float* __restrict__ Wk, const float* __restrict__ Wv,
    const float* __restrict__ Wo, short* __restrict__ x16,
    short* __restrict__ WT, short* __restrict__ WoT, int n8) {
    if ((int)blockIdx.x < 2048) {
        const int i = blockIdx.x * 256 + threadIdx.x;
        if (i >= n8) return;
        const float4 a = reinterpret_cast<const float4*>(x)[2 * i];
        const float4 b = reinterpret_cast<const float4*>(x)[2 * i + 1];
        short8 o;
        o[0] = f2bf(a.x); o[1] = f2bf(a.y); o[2] = f2bf(a.z); o[3] = f2bf(a.w);
        o[4] = f2bf(b.x); o[5] = f2bf(b.y); o[6] = f2bf(b.z); o[7] = f2bf(b.w);
        reinterpret_cast<short8*>(x16)[i] = o;
        return;
    }
    __shared__ short tl[64][65];
    int t = blockIdx.x - 2048;
    const float* src; short* dst; int N, nx;
    if (t < 256)      { src = Wq; dst = WT;                N = 1024; nx = 16; }
    else if (t < 320) { src = Wk; dst = WT + 1024 * 1024;  N = 256;  nx = 4;  t -= 256; }
    else if (t < 384) { src = Wv; dst = WT + 1280 * 1024;  N = 256;  nx = 4;  t -= 320; }
    else              { src = Wo; dst = WoT;               N = 1024; nx = 16; t -= 384; }
    const int n0 = (t % nx) * 64, k0 = (t / nx) * 64;
    const int tid = threadIdx.x;

    #pragma unroll
    for (int i = 0; i < 4; ++i) {
        const int kr = (tid >> 4) + i * 16;
        const int c4 = (tid & 15) * 4;
        const float4 v = *reinterpret_cast<const float4*>(
            &src[(size_t)(k0 + kr) * N + n0 + c4]);
        tl[kr][c4 + 0] = f2bf(v.x);
        tl[kr][c4 + 1] = f2bf(v.y);
        tl[kr][c4 + 2] = f2bf(v.z);
        tl[kr][c4 + 3] = f2bf(v.w);
    }
    __syncthreads();

    const int nr  = tid >> 2;
    const int kc0 = (tid & 3) * 16;
    short tmp[16];
    #pragma unroll
    for (int j = 0; j < 16; ++j) tmp[j] = tl[kc0 + j][nr];
    short8* outp = reinterpret_cast<short8*>(&dst[(size_t)(n0 + nr) * 1024 + k0 + kc0]);
    outp[0] = *reinterpret_cast<short8*>(&tmp[0]);
    outp[1] = *reinterpret_cast<short8*>(&tmp[8]);
}

// ---------------------------------------------------------------------------
// FUSED QKV GEMM + rope/rms/v-transpose epilogue (R18), with V key
// permutation updated for the 32x32 MFMA B-fragment map: within each
// 16-key group, key chunk g (4 keys) stored at offset {0,8,4,12}[g].
// ---------------------------------------------------------------------------
__global__ __launch_bounds__(256) void gemm_qkv_fused(
    const short* __restrict__ A, const short* __restrict__ BT,
    const float* __restrict__ cosb, const float* __restrict__ sinb,
    short* __restrict__ q16, short* __restrict__ k16, short* __restrict__ vT,
    int B, int T) {
    __shared__ short smem[2][(128 + 64) * 64];   // As | Bs, 48KB

    const int K = 1024;
    const int tid  = threadIdx.x;
    const int lane = tid & 63;
    const int w    = tid >> 6;
    const int lq = lane & 15, lh = lane >> 4;
    const int wm = w >> 1,   wn = w & 1;
    const size_t arow0 = (size_t)blockIdx.x * 128;
    const size_t brow0 = (size_t)blockIdx.y * 64;

    const int sr  = lane >> 3;
    const int sc  = lane & 7;
    const int scg = sc ^ sr;

    f32x4 acc[4][2];
    #pragma unroll
    for (int mi = 0; mi < 4; ++mi)
        #pragma unroll
        for (int ni = 0; ni < 2; ++ni) acc[mi][ni] = (f32x4){0.f, 0.f, 0.f, 0.f};

    const int NT = K >> 6;   // 16

    auto STAGE = [&](int u, int k0) {
        short* As = smem[u];
        short* Bs = smem[u] + 128 * 64;
        #pragma unroll
        for (int i = 0; i < 4; ++i) {
            const int rg = w * 4 + i;
            gload_lds16(A + (arow0 + rg * 8 + sr) * K + k0 + scg * 8,
                        &As[rg * 8 * 64]);
        }
        #pragma unroll
        for (int i = 0; i < 2; ++i) {
            const int rg = w * 2 + i;
            gload_lds16(BT + (brow0 + rg * 8 + sr) * K + k0 + scg * 8,
                        &Bs[rg * 8 * 64]);
        }
    };

    STAGE(0, 0);
    __syncthreads();
    int cur = 0;

    for (int t = 0; t < NT; ++t) {
        if (t + 1 < NT) STAGE(cur ^ 1, (t + 1) << 6);
        const short* As = smem[cur];
        const short* Bs = smem[cur] + 128 * 64;

        #pragma unroll
        for (int dk = 0; dk < 2; ++dk) {
            short8 af[4], bf[2];
            #pragma unroll
            for (int mi = 0; mi < 4; ++mi) {
                const int r = wm * 64 + mi * 16 + lq;
                af[mi] = *reinterpret_cast<const short8*>(
                    &As[r * 64 + (((dk * 4 + lh) ^ (lq & 7)) * 8)]);
            }
            #pragma unroll
            for (int ni = 0; ni < 2; ++ni) {
                const int r = wn * 32 + ni * 16 + lq;
                bf[ni] = *reinterpret_cast<const short8*>(
                    &Bs[r * 64 + (((dk * 4 + lh) ^ (lq & 7)) * 8)]);
            }
            __builtin_amdgcn_s_setprio(1);
            #pragma unroll
            for (int mi = 0; mi < 4; ++mi)
                #pragma unroll
                for (int ni = 0; ni < 2; ++ni)
                    acc[mi][ni] = __builtin_amdgcn_mfma_f32_16x16x32_bf16(
                        af[mi], bf[ni], acc[mi][ni], 0, 0, 0);
            __builtin_amdgcn_s_setprio(0);
        }

        __syncthreads();
        cur ^= 1;
    }

    // ---- epilogue: stash f32 tile [128][66-padded] in LDS ----
    float* fl = (float*)smem;   // 128*66*4 = 33792B <= 48KB
    #pragma unroll
    for (int mi = 0; mi < 4; ++mi) {
        const int row = wm * 64 + mi * 16 + lh * 4;
        #pragma unroll
        for (int ni = 0; ni < 2; ++ni) {
            const int col = wn * 32 + ni * 16 + lq;
            #pragma unroll
            for (int i = 0; i < 4; ++i)
                fl[(row + i) * 66 + col] = acc[mi][ni][i];
        }
    }
    __syncthreads();

    const int by = blockIdx.y;
    const int b  = (int)(arow0 / T);
    const int t0 = (int)(arow0 % T);

    if (by < 20) {
        // --- rope + rmsnorm; 2 rows/iter, 5-step half-wave reduce ---
        const int j  = lane & 31;
        const int rh = lane >> 5;
        for (int rr = 0; rr < 16; ++rr) {
            const int row = w * 32 + rr * 2 + rh;
            const int t   = t0 + row;
            const float x1 = fl[row * 66 + j];
            const float x2 = fl[row * 66 + 32 + j];
            const float c = cosb[t * 32 + j];
            const float s = sinb[t * 32 + j];
            const float y1 = x1 * c + x2 * s;
            const float y2 = x2 * c - x1 * s;
            float ss = y1 * y1 + y2 * y2;
            #pragma unroll
            for (int m = 1; m < 32; m <<= 1) ss += __shfl_xor(ss, m);
            const float r = rsqrtf(ss * (1.0f / 64.0f) + EPS);
            if (by < 16) {
                short* o = q16 + ((size_t)(b * 16 + by) * T + t) * 64;
                o[j]      = f2bf(y1 * r * (0.125f * LOG2E));
                o[j + 32] = f2bf(y2 * r * (0.125f * LOG2E));
            } else {
                short* o = k16 + ((size_t)(b * 4 + (by - 16)) * T + t) * 64;
                o[j]      = f2bf(y1 * r);
                o[j + 32] = f2bf(y2 * r);
            }
        }
    } else {
        // --- v: cast + transpose + 32x32-B-frag key-permute ---
        // within each 16-key group, key chunk g -> position {0,8,4,12}[g]
        const int kvh = by - 20;
        const int dim = tid >> 2;
        const int tq  = (tid & 3) * 16;   // 16-aligned group base
        short* orow = vT + ((size_t)(b * 4 + kvh) * 64 + dim) * T + t0;
        #pragma unroll
        for (int th = 0; th < 2; ++th) {
            short tmp[16];
            #pragma unroll
            for (int j2 = 0; j2 < 16; ++j2)
                tmp[j2] = f2bf(fl[(th * 64 + tq + j2) * 66 + dim]);
            #pragma unroll
            for (int g2 = 0; g2 < 4; ++g2) {
                const int pc = (g2 & 1) * 8 + (g2 >> 1) * 4;
                *reinterpret_cast<short4v*>(orow + th * 64 + tq + pc) =
                    *reinterpret_cast<short4v*>(&tmp[g2 * 4]);
            }
        }
    }
}

// ---------------------------------------------------------------------------
// bf16 MFMA GEMM (Wo): C f32 = A bf16 · B^T bf16. BK=64 (R16 proven).
// ---------------------------------------------------------------------------
__global__ __launch_bounds__(256) void gemm_wo(const short* __restrict__ A,
                                               const short* __restrict__ BT,
                                               float* __restrict__ C,
                                               int M, int N, int K) {
    __shared__ short smem[2][(128 + 64) * 64];

    const int tid  = threadIdx.x;
    const int lane = tid & 63;
    const int w    = tid >> 6;
    const int lq = lane & 15, lh = lane >> 4;
    const int wm = w >> 1,   wn = w & 1;
    const size_t arow0 = (size_t)blockIdx.x * 128;
    const size_t brow0 = (size_t)blockIdx.y * 64;

    const int sr  = lane >> 3;
    const int sc  = lane & 7;
    const int scg = sc ^ sr;

    f32x4 acc[4][2];
    #pragma unroll
    for (int mi = 0; mi < 4; ++mi)
        #pragma unroll
        for (int ni = 0; ni < 2; ++ni) acc[mi][ni] = (f32x4){0.f, 0.f, 0.f, 0.f};

    const int NT = K >> 6;

    auto STAGE = [&](int u, int k0) {
        short* As = smem[u];
        short* Bs = smem[u] + 128 * 64;
        #pragma unroll
        for (int i = 0; i < 4; ++i) {
            const int rg = w * 4 + i;
            gload_lds16(A + (arow0 + rg * 8 + sr) * K + k0 + scg * 8,
                        &As[rg * 8 * 64]);
        }
        #pragma unroll
        for (int i = 0; i < 2; ++i) {
            const int rg = w * 2 + i;
            gload_lds16(BT + (brow0 + rg * 8 + sr) * K + k0 + scg * 8,
                        &Bs[rg * 8 * 64]);
        }
    };

    STAGE(0, 0);
    __syncthreads();
    int cur = 0;

    for (int t = 0; t < NT; ++t) {
        if (t + 1 < NT) STAGE(cur ^ 1, (t + 1) << 6);
        const short* As = smem[cur];
        const short* Bs = smem[cur] + 128 * 64;

        #pragma unroll
        for (int dk = 0; dk < 2; ++dk) {
            short8 af[4], bf[2];
            #pragma unroll
            for (int mi = 0; mi < 4; ++mi) {
                const int r = wm * 64 + mi * 16 + lq;
                af[mi] = *reinterpret_cast<const short8*>(
                    &As[r * 64 + (((dk * 4 + lh) ^ (lq & 7)) * 8)]);
            }
            #pragma unroll
            for (int ni = 0; ni < 2; ++ni) {
                const int r = wn * 32 + ni * 16 + lq;
                bf[ni] = *reinterpret_cast<const short8*>(
                    &Bs[r * 64 + (((dk * 4 + lh) ^ (lq & 7)) * 8)]);
            }
            __builtin_amdgcn_s_setprio(1);
            #pragma unroll
            for (int mi = 0; mi < 4; ++mi)
                #pragma unroll
                for (int ni = 0; ni < 2; ++ni)
                    acc[mi][ni] = __builtin_amdgcn_mfma_f32_16x16x32_bf16(
                        af[mi], bf[ni], acc[mi][ni], 0, 0, 0);
            __builtin_amdgcn_s_setprio(0);
        }

        __syncthreads();
        cur ^= 1;
    }

    #pragma unroll
    for (int mi = 0; mi < 4; ++mi) {
        const size_t row = arow0 + wm * 64 + mi * 16 + lh * 4;
        #pragma unroll
        for (int ni = 0; ni < 2; ++ni) {
            const size_t col = brow0 + wn * 32 + ni * 16 + lq;
            #pragma unroll
            for (int i = 0; i < 4; ++i)
                C[(row + i) * N + col] = acc[mi][ni][i];
        }
    }
}

// ---------------------------------------------------------------------------
// bf16 MFMA flash attention — 32x32x16 MFMA, 1-wave blocks (64 thr), 32
// q-rows/wave, wave-private 16KB KV staging. Static-max softmax (exp2),
// l via VALU sum + shfl_xor(32). XCD-aware LPT grid (2048 blocks).
// A/B frag maps: row=lane&31, k=(lane>>5)*8+j; C/D: col=lane&31,
// row=(reg&3)+8*(reg>>2)+4*(lane>>5). P feeds PV in-register via the
// key-permuted vT16 (no cross-lane ops).
// ---------------------------------------------------------------------------
__global__ __launch_bounds__(64) void attn_mfma(
    const short* __restrict__ q16, const short* __restrict__ k16,
    const short* __restrict__ vT16, short* __restrict__ att16, int B, int T) {
    __shared__ short Kt[64 * 64];
    __shared__ short Vt[64 * 64];

    const int lane = threadIdx.x & 63;
    const int lq32 = lane & 31;
    const int hi   = lane >> 5;

    const int idx = blockIdx.x;
    const int g   = idx & 7;             // b*4 + hk (8 KV-groups = 8 XCDs)
    const int jj  = idx >> 3;
    const int b   = g >> 2;
    const int hk  = g & 3;
    const int qs  = (T >> 5) - 1 - (jj >> 2);   // 63..0 LPT
    const int h   = hk * 4 + (jj & 3);
    const int t0  = qs * 32;
    const int nt  = (qs >> 1) + 1;
    const bool evenq = !(qs & 1);

    // Q fragments: B-operand, 4 k-steps of 16 dims
    const short* qrow = q16 + ((size_t)(b * 16 + h) * T + t0 + lq32) * 64;
    short8 qf[4];
    #pragma unroll
    for (int s = 0; s < 4; ++s)
        qf[s] = *reinterpret_cast<const short8*>(qrow + s * 16 + hi * 8);

    const short* kg = k16 + (size_t)(b * 4 + hk) * T * 64;
    const short* vg = vT16 + (size_t)(b * 4 + hk) * 64 * T;

    const int sr  = lane >> 3;           // 0..7
    const int sc  = lane & 7;
    const int scg = sc ^ sr;             // pre-swizzled global chunk

    f32x16 yacc0, yacc1;
    #pragma unroll
    for (int r = 0; r < 16; ++r) { yacc0[r] = 0.f; yacc1[r] = 0.f; }
    float lsum = 0.f;

    for (int ti = 0; ti < nt; ++ti) {
        const int s0 = ti * 64;
        const bool last = (ti == nt - 1);
        const bool do1  = !(last && evenq);   // upper 32 keys active?

        __syncthreads();   // prior tile's LDS reads drained (1-wave: cheap)
        #pragma unroll
        for (int i = 0; i < 8; ++i)
            gload_lds16(kg + (size_t)(s0 + i * 8 + sr) * 64 + scg * 8,
                        &Kt[i * 8 * 64]);
        #pragma unroll
        for (int i = 0; i < 8; ++i)
            gload_lds16(vg + (size_t)(i * 8 + sr) * T + s0 + scg * 8,
                        &Vt[i * 8 * 64]);
        asm volatile("s_waitcnt vmcnt(0)" ::: "memory");
        __builtin_amdgcn_sched_barrier(0);
        __syncthreads();

        // --- QK^T: S^T[key][q], 32x32 tiles ---
        f32x16 st0, st1;
        #pragma unroll
        for (int r = 0; r < 16; ++r) { st0[r] = 0.f; st1[r] = 0.f; }
        __builtin_amdgcn_s_setprio(1);
        #pragma unroll
        for (int s = 0; s < 4; ++s) {
            const int c = s * 2 + hi;
            const short8 kf0 = *reinterpret_cast<const short8*>(
                (const char*)Kt + lq32 * 128 + ((c ^ (lq32 & 7)) * 16));
            st0 = __builtin_amdgcn_mfma_f32_32x32x16_bf16(kf0, qf[s], st0, 0, 0, 0);
        }
        if (do1) {
            #pragma unroll
            for (int s = 0; s < 4; ++s) {
                const int c = s * 2 + hi;
                const short8 kf1 = *reinterpret_cast<const short8*>(
                    (const char*)Kt + (32 + lq32) * 128 + ((c ^ (lq32 & 7)) * 16));
                st1 = __builtin_amdgcn_mfma_f32_32x32x16_bf16(kf1, qf[s], st1, 0, 0, 0);
            }
        }
        __builtin_amdgcn_s_setprio(0);

        // --- causal mask on diagonal 32x32 tile ---
        if (last) {
            if (evenq) {
                #pragma unroll
                for (int r = 0; r < 16; ++r) {
                    const int key = (r & 3) + 8 * (r >> 2) + 4 * hi;
                    if (key > lq32) st0[r] = -1e30f;
                }
            } else {
                #pragma unroll
                for (int r = 0; r < 16; ++r) {
                    const int key = (r & 3) + 8 * (r >> 2) + 4 * hi;
                    if (key > lq32) st1[r] = -1e30f;
                }
            }
        }

        // --- p = exp2(s); lsum; pack (B-frag order matches permuted V) ---
        union pk_t { short8 s8; __hip_bfloat162 h2[4]; };
        pk_t pA0, pA1, pB0, pB1;
        #pragma unroll
        for (int r = 0; r < 16; ++r) { st0[r] = exp2f(st0[r]); lsum += st0[r]; }
        #pragma unroll
        for (int i = 0; i < 4; ++i) {
            pA0.h2[i] = __float22bfloat162_rn(float2{st0[2 * i], st0[2 * i + 1]});
            pA1.h2[i] = __float22bfloat162_rn(float2{st0[8 + 2 * i], st0[8 + 2 * i + 1]});
        }
        if (do1) {
            #pragma unroll
            for (int r = 0; r < 16; ++r) { st1[r] = exp2f(st1[r]); lsum += st1[r]; }
            #pragma unroll
            for (int i = 0; i < 4; ++i) {
                pB0.h2[i] = __float22bfloat162_rn(float2{st1[2 * i], st1[2 * i + 1]});
                pB1.h2[i] = __float22bfloat162_rn(float2{st1[8 + 2 * i], st1[8 + 2 * i + 1]});
            }
        }

        // --- PV: Y^T[dim][q] += V^T · P, 2 dim-tiles x (2 or 4) k-steps ---
        __builtin_amdgcn_s_setprio(1);
        #pragma unroll
        for (int dt = 0; dt < 2; ++dt) {
            const int row = dt * 32 + lq32;
            const int sw  = lq32 & 7;
            const short8 vf0 = *reinterpret_cast<const short8*>(
                (const char*)Vt + row * 128 + (((hi) ^ sw) * 16));
            const short8 vf1 = *reinterpret_cast<const short8*>(
                (const char*)Vt + row * 128 + (((2 + hi) ^ sw) * 16));
            if (dt == 0) {
                yacc0 = __builtin_amdgcn_mfma_f32_32x32x16_bf16(vf0, pA0.s8, yacc0, 0, 0, 0);
                yacc0 = __builtin_amdgcn_mfma_f32_32x32x16_bf16(vf1, pA1.s8, yacc0, 0, 0, 0);
            } else {
                yacc1 = __builtin_amdgcn_mfma_f32_32x32x16_bf16(vf0, pA0.s8, yacc1, 0, 0, 0);
                yacc1 = __builtin_amdgcn_mfma_f32_32x32x16_bf16(vf1, pA1.s8, yacc1, 0, 0, 0);
            }
            if (do1) {
                const short8 vf2 = *reinterpret_cast<const short8*>(
                    (const char*)Vt + row * 128 + (((4 + hi) ^ sw) * 16));
                const short8 vf3 = *reinterpret_cast<const short8*>(
                    (const char*)Vt + row * 128 + (((6 + hi) ^ sw) * 16));
                if (dt == 0) {
                    yacc0 = __builtin_amdgcn_mfma_f32_32x32x16_bf16(vf2, pB0.s8, yacc0, 0, 0, 0);
                    yacc0 = __builtin_amdgcn_mfma_f32_32x32x16_bf16(vf3, pB1.s8, yacc0, 0, 0, 0);
                } else {
                    yacc1 = __builtin_amdgcn_mfma_f32_32x32x16_bf16(vf2, pB0.s8, yacc1, 0, 0, 0);
                    yacc1 = __builtin_amdgcn_mfma_f32_32x32x16_bf16(vf3, pB1.s8, yacc1, 0, 0, 0);
                }
            }
        }
        __builtin_amdgcn_s_setprio(0);
    }

    // --- epilogue ---
    lsum += __shfl_xor(lsum, 32);
    const float inv = 1.f / lsum;
    short* orow = att16 + (((size_t)b * T + t0 + lq32) * 16 + h) * 64;
    #pragma unroll
    for (int i = 0; i < 4; ++i) {
        short4v o0, o1;
        #pragma unroll
        for (int j2 = 0; j2 < 4; ++j2) {
            o0[j2] = f2bf(yacc0[4 * i + j2] * inv);
            o1[j2] = f2bf(yacc1[4 * i + j2] * inv);
        }
        *reinterpret_cast<short4v*>(orow + i * 8 + hi * 4)      = o0;
        *reinterpret_cast<short4v*>(orow + 32 + i * 8 + hi * 4) = o1;
    }
}

// ---------------------------------------------------------------------------
extern "C" void kernel_launch(void* const* d_in, const int* in_sizes, int n_in,
                              void* d_out, int out_size, void* d_ws, size_t ws_size,
                              hipStream_t stream) {
    const float* x    = (const float*)d_in[0];
    const float* cosb = (const float*)d_in[1];
    const float* sinb = (const float*)d_in[2];
    const float* Wq   = (const float*)d_in[3];
    const float* Wk   = (const float*)d_in[4];
    const float* Wv   = (const float*)d_in[5];
    const float* Wo   = (const float*)d_in[6];
    float* out = (float*)d_out;

    const int B = 2, T = 2048;
    const int M = B * T;   // 4096
    const size_t MB = 1 << 20;

    char* wsb = (char*)d_ws;
    short* att16 = (short*)(wsb);
    short* q16   = (short*)(wsb + 8 * MB);
    short* k16   = (short*)(wsb + 16 * MB);
    short* vT16  = (short*)(wsb + 18 * MB);
    short* x16   = (short*)(wsb + 24 * MB);
    short* WT    = (short*)(wsb + 32 * MB);
    short* WoT   = (short*)(wsb + 36 * MB);

    // x cast + all weight transposes, one dispatch
    prep_inputs<<<2048 + 640, 256, 0, stream>>>(x, Wq, Wk, Wv, Wo,
                                                x16, WT, WoT, M * 1024 / 8);

    // fused QKV GEMM + rope/rms/v-transpose epilogue: grid (M/128, 24)
    gemm_qkv_fused<<<dim3(M / 128, 1536 / 64), 256, 0, stream>>>(
        x16, WT, cosb, sinb, q16, k16, vT16, B, T);

    // flash attention: 32x32 MFMA, 1-wave blocks, 2048 blocks x 64 threads
    attn_mfma<<<dim3((T / 32) * 16 * B), 64, 0, stream>>>(q16, k16, vT16, att16, B, T);

    // Wo GEMM: f32 output
    gemm_wo<<<dim3(M / 128, 1024 / 64), 256, 0, stream>>>(
        att16, WoT, out, M, 1024, 1024);
}

// Round 21
// 94.413 us; speedup vs baseline: 1.1060x; 1.1060x over previous
//
#include <hip/hip_runtime.h>
#include <hip/hip_bf16.h>
#include <math.h>

#define EPS 1e-6f
#define LOG2E 1.44269504088896340736f

typedef __attribute__((ext_vector_type(8))) short short8;
typedef __attribute__((ext_vector_type(4))) short short4v;
typedef __attribute__((ext_vector_type(4))) float f32x4;

// f32 -> bf16 (round-to-nearest-even)
static __device__ __forceinline__ short f2bf(float x) {
    unsigned u = __builtin_bit_cast(unsigned, x);
    u += 0x7fffu + ((u >> 16) & 1u);
    return (short)(u >> 16);
}
// bf16 -> f32
static __device__ __forceinline__ float bf2f(short s) {
    unsigned u = ((unsigned)(unsigned short)s) << 16;
    return __builtin_bit_cast(float, u);
}

typedef __attribute__((address_space(1))) const void gvoid_t;
typedef __attribute__((address_space(3))) void lvoid_t;
static __device__ __forceinline__ void gload_lds16(const void* g, void* l) {
    __builtin_amdgcn_global_load_lds((gvoid_t*)g, (lvoid_t*)l, 16, 0, 0);
}

// ---------------------------------------------------------------------------
// Combined input prep: x cast (blocks [0,2048)) + all 4 weight transposes
// (blocks [2048, 2688)) in one dispatch.
// ---------------------------------------------------------------------------
__global__ __launch_bounds__(256) void prep_inputs(
    const float* __restrict__ x, const float* __restrict__ Wq,
    const float* __restrict__ Wk, const float* __restrict__ Wv,
    const float* __restrict__ Wo, short* __restrict__ x16,
    short* __restrict__ WT, short* __restrict__ WoT, int n8) {
    if ((int)blockIdx.x < 2048) {
        const int i = blockIdx.x * 256 + threadIdx.x;
        if (i >= n8) return;
        const float4 a = reinterpret_cast<const float4*>(x)[2 * i];
        const float4 b = reinterpret_cast<const float4*>(x)[2 * i + 1];
        short8 o;
        o[0] = f2bf(a.x); o[1] = f2bf(a.y); o[2] = f2bf(a.z); o[3] = f2bf(a.w);
        o[4] = f2bf(b.x); o[5] = f2bf(b.y); o[6] = f2bf(b.z); o[7] = f2bf(b.w);
        reinterpret_cast<short8*>(x16)[i] = o;
        return;
    }
    __shared__ short tl[64][65];
    int t = blockIdx.x - 2048;
    const float* src; short* dst; int N, nx;
    if (t < 256)      { src = Wq; dst = WT;                N = 1024; nx = 16; }
    else if (t < 320) { src = Wk; dst = WT + 1024 * 1024;  N = 256;  nx = 4;  t -= 256; }
    else if (t < 384) { src = Wv; dst = WT + 1280 * 1024;  N = 256;  nx = 4;  t -= 320; }
    else              { src = Wo; dst = WoT;               N = 1024; nx = 16; t -= 384; }
    const int n0 = (t % nx) * 64, k0 = (t / nx) * 64;
    const int tid = threadIdx.x;

    #pragma unroll
    for (int i = 0; i < 4; ++i) {
        const int kr = (tid >> 4) + i * 16;
        const int c4 = (tid & 15) * 4;
        const float4 v = *reinterpret_cast<const float4*>(
            &src[(size_t)(k0 + kr) * N + n0 + c4]);
        tl[kr][c4 + 0] = f2bf(v.x);
        tl[kr][c4 + 1] = f2bf(v.y);
        tl[kr][c4 + 2] = f2bf(v.z);
        tl[kr][c4 + 3] = f2bf(v.w);
    }
    __syncthreads();

    const int nr  = tid >> 2;
    const int kc0 = (tid & 3) * 16;
    short tmp[16];
    #pragma unroll
    for (int j = 0; j < 16; ++j) tmp[j] = tl[kc0 + j][nr];
    short8* outp = reinterpret_cast<short8*>(&dst[(size_t)(n0 + nr) * 1024 + k0 + kc0]);
    outp[0] = *reinterpret_cast<short8*>(&tmp[0]);
    outp[1] = *reinterpret_cast<short8*>(&tmp[8]);
}

// ---------------------------------------------------------------------------
// FUSED QKV GEMM + rope/rms/v-transpose epilogue; rope parallelized
// (2 rows/iter, 5-step half-wave reduce). V key-permute for the 16x16
// P-fragment map: key (hi*16+g*4+i) stored at (g*8+hi*4+i).
// ---------------------------------------------------------------------------
__global__ __launch_bounds__(256) void gemm_qkv_fused(
    const short* __restrict__ A, const short* __restrict__ BT,
    const float* __restrict__ cosb, const float* __restrict__ sinb,
    short* __restrict__ q16, short* __restrict__ k16, short* __restrict__ vT,
    int B, int T) {
    __shared__ short smem[2][(128 + 64) * 64];   // As | Bs, 48KB

    const int K = 1024;
    const int tid  = threadIdx.x;
    const int lane = tid & 63;
    const int w    = tid >> 6;
    const int lq = lane & 15, lh = lane >> 4;
    const int wm = w >> 1,   wn = w & 1;
    const size_t arow0 = (size_t)blockIdx.x * 128;
    const size_t brow0 = (size_t)blockIdx.y * 64;

    const int sr  = lane >> 3;
    const int sc  = lane & 7;
    const int scg = sc ^ sr;

    f32x4 acc[4][2];
    #pragma unroll
    for (int mi = 0; mi < 4; ++mi)
        #pragma unroll
        for (int ni = 0; ni < 2; ++ni) acc[mi][ni] = (f32x4){0.f, 0.f, 0.f, 0.f};

    const int NT = K >> 6;   // 16

    auto STAGE = [&](int u, int k0) {
        short* As = smem[u];
        short* Bs = smem[u] + 128 * 64;
        #pragma unroll
        for (int i = 0; i < 4; ++i) {
            const int rg = w * 4 + i;
            gload_lds16(A + (arow0 + rg * 8 + sr) * K + k0 + scg * 8,
                        &As[rg * 8 * 64]);
        }
        #pragma unroll
        for (int i = 0; i < 2; ++i) {
            const int rg = w * 2 + i;
            gload_lds16(BT + (brow0 + rg * 8 + sr) * K + k0 + scg * 8,
                        &Bs[rg * 8 * 64]);
        }
    };

    STAGE(0, 0);
    __syncthreads();
    int cur = 0;

    for (int t = 0; t < NT; ++t) {
        if (t + 1 < NT) STAGE(cur ^ 1, (t + 1) << 6);
        const short* As = smem[cur];
        const short* Bs = smem[cur] + 128 * 64;

        #pragma unroll
        for (int dk = 0; dk < 2; ++dk) {
            short8 af[4], bf[2];
            #pragma unroll
            for (int mi = 0; mi < 4; ++mi) {
                const int r = wm * 64 + mi * 16 + lq;
                af[mi] = *reinterpret_cast<const short8*>(
                    &As[r * 64 + (((dk * 4 + lh) ^ (lq & 7)) * 8)]);
            }
            #pragma unroll
            for (int ni = 0; ni < 2; ++ni) {
                const int r = wn * 32 + ni * 16 + lq;
                bf[ni] = *reinterpret_cast<const short8*>(
                    &Bs[r * 64 + (((dk * 4 + lh) ^ (lq & 7)) * 8)]);
            }
            __builtin_amdgcn_s_setprio(1);
            #pragma unroll
            for (int mi = 0; mi < 4; ++mi)
                #pragma unroll
                for (int ni = 0; ni < 2; ++ni)
                    acc[mi][ni] = __builtin_amdgcn_mfma_f32_16x16x32_bf16(
                        af[mi], bf[ni], acc[mi][ni], 0, 0, 0);
            __builtin_amdgcn_s_setprio(0);
        }

        __syncthreads();
        cur ^= 1;
    }

    // ---- epilogue: stash f32 tile [128][66-padded] in LDS ----
    float* fl = (float*)smem;   // 128*66*4 = 33792B <= 48KB
    #pragma unroll
    for (int mi = 0; mi < 4; ++mi) {
        const int row = wm * 64 + mi * 16 + lh * 4;
        #pragma unroll
        for (int ni = 0; ni < 2; ++ni) {
            const int col = wn * 32 + ni * 16 + lq;
            #pragma unroll
            for (int i = 0; i < 4; ++i)
                fl[(row + i) * 66 + col] = acc[mi][ni][i];
        }
    }
    __syncthreads();

    const int by = blockIdx.y;
    const int b  = (int)(arow0 / T);
    const int t0 = (int)(arow0 % T);

    if (by < 20) {
        // --- rope + rmsnorm; 2 rows/iter, 5-step half-wave reduce ---
        const int j  = lane & 31;
        const int rh = lane >> 5;
        for (int rr = 0; rr < 16; ++rr) {
            const int row = w * 32 + rr * 2 + rh;
            const int t   = t0 + row;
            const float x1 = fl[row * 66 + j];
            const float x2 = fl[row * 66 + 32 + j];
            const float c = cosb[t * 32 + j];
            const float s = sinb[t * 32 + j];
            const float y1 = x1 * c + x2 * s;
            const float y2 = x2 * c - x1 * s;
            float ss = y1 * y1 + y2 * y2;
            #pragma unroll
            for (int m = 1; m < 32; m <<= 1) ss += __shfl_xor(ss, m);
            const float r = rsqrtf(ss * (1.0f / 64.0f) + EPS);
            if (by < 16) {
                short* o = q16 + ((size_t)(b * 16 + by) * T + t) * 64;
                o[j]      = f2bf(y1 * r * (0.125f * LOG2E));
                o[j + 32] = f2bf(y2 * r * (0.125f * LOG2E));
            } else {
                short* o = k16 + ((size_t)(b * 4 + (by - 16)) * T + t) * 64;
                o[j]      = f2bf(y1 * r);
                o[j + 32] = f2bf(y2 * r);
            }
        }
    } else {
        // --- v: cast + transpose + key-permute (16x16 P-frag map) ---
        const int kvh = by - 20;
        const int dim = tid >> 2;
        const int tq  = (tid & 3) * 16;
        const int hi  = (tq >> 4) & 1;
        const int a32 = tq & 32;
        short* orow = vT + ((size_t)(b * 4 + kvh) * 64 + dim) * T + t0;
        #pragma unroll
        for (int th = 0; th < 2; ++th) {
            short tmp[16];
            #pragma unroll
            for (int j2 = 0; j2 < 16; ++j2)
                tmp[j2] = f2bf(fl[(th * 64 + tq + j2) * 66 + dim]);
            #pragma unroll
            for (int g = 0; g < 4; ++g)
                *reinterpret_cast<short4v*>(orow + th * 64 + a32 + g * 8 + hi * 4) =
                    *reinterpret_cast<short4v*>(&tmp[g * 4]);
        }
    }
}

// ---------------------------------------------------------------------------
// bf16 MFMA GEMM (Wo): C f32 = A bf16 · B^T bf16. BK=64 (R16 proven).
// ---------------------------------------------------------------------------
__global__ __launch_bounds__(256) void gemm_wo(const short* __restrict__ A,
                                               const short* __restrict__ BT,
                                               float* __restrict__ C,
                                               int M, int N, int K) {
    __shared__ short smem[2][(128 + 64) * 64];

    const int tid  = threadIdx.x;
    const int lane = tid & 63;
    const int w    = tid >> 6;
    const int lq = lane & 15, lh = lane >> 4;
    const int wm = w >> 1,   wn = w & 1;
    const size_t arow0 = (size_t)blockIdx.x * 128;
    const size_t brow0 = (size_t)blockIdx.y * 64;

    const int sr  = lane >> 3;
    const int sc  = lane & 7;
    const int scg = sc ^ sr;

    f32x4 acc[4][2];
    #pragma unroll
    for (int mi = 0; mi < 4; ++mi)
        #pragma unroll
        for (int ni = 0; ni < 2; ++ni) acc[mi][ni] = (f32x4){0.f, 0.f, 0.f, 0.f};

    const int NT = K >> 6;

    auto STAGE = [&](int u, int k0) {
        short* As = smem[u];
        short* Bs = smem[u] + 128 * 64;
        #pragma unroll
        for (int i = 0; i < 4; ++i) {
            const int rg = w * 4 + i;
            gload_lds16(A + (arow0 + rg * 8 + sr) * K + k0 + scg * 8,
                        &As[rg * 8 * 64]);
        }
        #pragma unroll
        for (int i = 0; i < 2; ++i) {
            const int rg = w * 2 + i;
            gload_lds16(BT + (brow0 + rg * 8 + sr) * K + k0 + scg * 8,
                        &Bs[rg * 8 * 64]);
        }
    };

    STAGE(0, 0);
    __syncthreads();
    int cur = 0;

    for (int t = 0; t < NT; ++t) {
        if (t + 1 < NT) STAGE(cur ^ 1, (t + 1) << 6);
        const short* As = smem[cur];
        const short* Bs = smem[cur] + 128 * 64;

        #pragma unroll
        for (int dk = 0; dk < 2; ++dk) {
            short8 af[4], bf[2];
            #pragma unroll
            for (int mi = 0; mi < 4; ++mi) {
                const int r = wm * 64 + mi * 16 + lq;
                af[mi] = *reinterpret_cast<const short8*>(
                    &As[r * 64 + (((dk * 4 + lh) ^ (lq & 7)) * 8)]);
            }
            #pragma unroll
            for (int ni = 0; ni < 2; ++ni) {
                const int r = wn * 32 + ni * 16 + lq;
                bf[ni] = *reinterpret_cast<const short8*>(
                    &Bs[r * 64 + (((dk * 4 + lh) ^ (lq & 7)) * 8)]);
            }
            __builtin_amdgcn_s_setprio(1);
            #pragma unroll
            for (int mi = 0; mi < 4; ++mi)
                #pragma unroll
                for (int ni = 0; ni < 2; ++ni)
                    acc[mi][ni] = __builtin_amdgcn_mfma_f32_16x16x32_bf16(
                        af[mi], bf[ni], acc[mi][ni], 0, 0, 0);
            __builtin_amdgcn_s_setprio(0);
        }

        __syncthreads();
        cur ^= 1;
    }

    #pragma unroll
    for (int mi = 0; mi < 4; ++mi) {
        const size_t row = arow0 + wm * 64 + mi * 16 + lh * 4;
        #pragma unroll
        for (int ni = 0; ni < 2; ++ni) {
            const size_t col = brow0 + wn * 32 + ni * 16 + lq;
            #pragma unroll
            for (int i = 0; i < 4; ++i)
                C[(row + i) * N + col] = acc[mi][ni][i];
        }
    }
}

// ---------------------------------------------------------------------------
// bf16 MFMA flash attention — R14/R18 champion verbatim: 2 waves x 16
// q-rows, single 16KB LDS buffer, static-max softmax (exp2 direct),
// l via ones-MFMA; XCD-aware mapping idx = j*8 + g, g = b*4+hk.
// ---------------------------------------------------------------------------
__global__ __launch_bounds__(128) void attn_mfma(
    const short* __restrict__ q16, const short* __restrict__ k16,
    const short* __restrict__ vT16, short* __restrict__ att16, int B, int T) {
    __shared__ short Kt[64 * 64];
    __shared__ short Vt[64 * 64];

    const int tid  = threadIdx.x;
    const int lane = tid & 63;
    const int w    = tid >> 6;
    const int lq   = lane & 15;
    const int lh   = lane >> 4;

    const int idx = blockIdx.x;
    const int g   = idx & 7;
    const int j   = idx >> 3;
    const int b   = g >> 2;
    const int hk  = g & 3;
    const int qs  = (T >> 5) - 1 - (j >> 2);
    const int h   = hk * 4 + (j & 3);
    const int t0w = qs * 32 + w * 16;
    const int nt  = (qs >> 1) + 1;
    const bool evenq = !(qs & 1);

    const short* qrow = q16 + ((size_t)(b * 16 + h) * T + t0w + lq) * 64;
    const short8 qf0 = *reinterpret_cast<const short8*>(qrow + lh * 8);
    const short8 qf1 = *reinterpret_cast<const short8*>(qrow + 32 + lh * 8);

    const short* kgbase = k16 + (size_t)(b * 4 + hk) * T * 64;
    const short* vgbase = vT16 + (size_t)(b * 4 + hk) * 64 * T;

    const int sr  = lane >> 3;
    const int sc  = lane & 7;
    const int scg = sc ^ sr;

    short8 ones;
    #pragma unroll
    for (int i = 0; i < 8; ++i) ones[i] = (short)0x3F80;

    f32x4 yacc[4];
    #pragma unroll
    for (int dt = 0; dt < 4; ++dt) yacc[dt] = (f32x4){0.f, 0.f, 0.f, 0.f};
    f32x4 lacc = (f32x4){0.f, 0.f, 0.f, 0.f};

    for (int ti = 0; ti < nt; ++ti) {
        const int s0 = ti * 64;
        const bool last = (ti == nt - 1);
        const int kmax = (last && evenq) ? 2 : 4;
        __syncthreads();
        #pragma unroll
        for (int p2 = 0; p2 < 4; ++p2) {
            const int r = w * 32 + p2 * 8 + sr;
            gload_lds16(kgbase + (size_t)(s0 + r) * 64 + scg * 8,
                        &Kt[(w * 32 + p2 * 8) * 64]);
            gload_lds16(vgbase + (size_t)r * T + s0 + scg * 8,
                        &Vt[(w * 32 + p2 * 8) * 64]);
        }
        __syncthreads();

        f32x4 st[4];
        __builtin_amdgcn_s_setprio(1);
        #pragma unroll
        for (int ks = 0; ks < 4; ++ks) if (ks < kmax) {
            f32x4 a1 = (f32x4){0.f, 0.f, 0.f, 0.f};
            #pragma unroll
            for (int dk = 0; dk < 2; ++dk) {
                const short8 kfr = *reinterpret_cast<const short8*>(
                    (char*)Kt + (ks * 16 + lq) * 128 +
                    (((dk * 4 + lh) ^ (lq & 7)) * 16));
                a1 = __builtin_amdgcn_mfma_f32_16x16x32_bf16(
                    kfr, dk ? qf1 : qf0, a1, 0, 0, 0);
            }
            st[ks] = a1;
        }
        __builtin_amdgcn_s_setprio(0);

        if (last) {
            const int rloc = (qs & 1) * 32 + w * 16 + lq;
            #pragma unroll
            for (int ks = 0; ks < 4; ++ks) if (ks < kmax)
                #pragma unroll
                for (int i2 = 0; i2 < 4; ++i2)
                    if (ks * 16 + lh * 4 + i2 > rloc)
                        st[ks][i2] = -1e30f;
        }

        union { short8 s8; __hip_bfloat162 h2[4]; } pf[2];
        #pragma unroll
        for (int ks2 = 0; ks2 < 2; ++ks2) if (ks2 * 2 < kmax) {
            #pragma unroll
            for (int ks = 2 * ks2; ks < 2 * ks2 + 2; ++ks)
                #pragma unroll
                for (int i2 = 0; i2 < 4; ++i2)
                    st[ks][i2] = exp2f(st[ks][i2]);
            pf[ks2].h2[0] = __float22bfloat162_rn(float2{st[2 * ks2][0], st[2 * ks2][1]});
            pf[ks2].h2[1] = __float22bfloat162_rn(float2{st[2 * ks2][2], st[2 * ks2][3]});
            pf[ks2].h2[2] = __float22bfloat162_rn(float2{st[2 * ks2 + 1][0], st[2 * ks2 + 1][1]});
            pf[ks2].h2[3] = __float22bfloat162_rn(float2{st[2 * ks2 + 1][2], st[2 * ks2 + 1][3]});
        }

        __builtin_amdgcn_s_setprio(1);
        #pragma unroll
        for (int ks2 = 0; ks2 < 2; ++ks2) if (ks2 * 2 < kmax)
            lacc = __builtin_amdgcn_mfma_f32_16x16x32_bf16(ones, pf[ks2].s8, lacc, 0, 0, 0);
        #pragma unroll
        for (int dt = 0; dt < 4; ++dt) {
            const int rb = (dt * 16 + lq) * 128;
            const int sw = lq & 7;
            #pragma unroll
            for (int ks2 = 0; ks2 < 2; ++ks2) if (ks2 * 2 < kmax) {
                const short8 vf = *reinterpret_cast<const short8*>(
                    (const char*)Vt + rb + (((ks2 * 4 + lh) ^ sw) * 16));
                yacc[dt] = __builtin_amdgcn_mfma_f32_16x16x32_bf16(
                    vf, pf[ks2].s8, yacc[dt], 0, 0, 0);
            }
        }
        __builtin_amdgcn_s_setprio(0);
    }

    const float inv = 1.f / lacc[0];
    short* orow = att16 + (((size_t)b * T + t0w + lq) * 16 + h) * 64;
    #pragma unroll
    for (int dt = 0; dt < 4; ++dt) {
        short4v o;
        o[0] = f2bf(yacc[dt][0] * inv);
        o[1] = f2bf(yacc[dt][1] * inv);
        o[2] = f2bf(yacc[dt][2] * inv);
        o[3] = f2bf(yacc[dt][3] * inv);
        *reinterpret_cast<short4v*>(orow + dt * 16 + lh * 4) = o;
    }
}

// ---------------------------------------------------------------------------
extern "C" void kernel_launch(void* const* d_in, const int* in_sizes, int n_in,
                              void* d_out, int out_size, void* d_ws, size_t ws_size,
                              hipStream_t stream) {
    const float* x    = (const float*)d_in[0];
    const float* cosb = (const float*)d_in[1];
    const float* sinb = (const float*)d_in[2];
    const float* Wq   = (const float*)d_in[3];
    const float* Wk   = (const float*)d_in[4];
    const float* Wv   = (const float*)d_in[5];
    const float* Wo   = (const float*)d_in[6];
    float* out = (float*)d_out;

    const int B = 2, T = 2048;
    const int M = B * T;   // 4096
    const size_t MB = 1 << 20;

    char* wsb = (char*)d_ws;
    short* att16 = (short*)(wsb);
    short* q16   = (short*)(wsb + 8 * MB);
    short* k16   = (short*)(wsb + 16 * MB);
    short* vT16  = (short*)(wsb + 18 * MB);
    short* x16   = (short*)(wsb + 24 * MB);
    short* WT    = (short*)(wsb + 32 * MB);
    short* WoT   = (short*)(wsb + 36 * MB);

    // x cast + all weight transposes, one dispatch
    prep_inputs<<<2048 + 640, 256, 0, stream>>>(x, Wq, Wk, Wv, Wo,
                                                x16, WT, WoT, M * 1024 / 8);

    // fused QKV GEMM + rope/rms/v-transpose epilogue: grid (M/128, 24)
    gemm_qkv_fused<<<dim3(M / 128, 1536 / 64), 256, 0, stream>>>(
        x16, WT, cosb, sinb, q16, k16, vT16, B, T);

    // flash attention (R14/R18 champion)
    attn_mfma<<<dim3((T / 32) * 16 * B), 128, 0, stream>>>(q16, k16, vT16, att16, B, T);

    // Wo GEMM: f32 output
    gemm_wo<<<dim3(M / 128, 1024 / 64), 256, 0, stream>>>(
        att16, WoT, out, M, 1024, 1024);
}